// Round 1
// baseline (228.605 us; speedup 1.0000x reference)
//
#include <hip/hip_runtime.h>
#include <hip/hip_bf16.h>

typedef __bf16 bf16x8 __attribute__((ext_vector_type(8)));
typedef float f32x4 __attribute__((ext_vector_type(4)));

#define NB 8
#define ND 512
#define NT 2048
#define NCODES 4096
#define NM (NB * NT)          // 16384 rows
#define MARGIN_F 0.2f
#define ENC_STRIDE 320

#define BM 128
#define BN 128
#define BK 32
#define LDT 40                // padded LDS row stride in bf16 elems (80 B: 16B-aligned, 2-way bank alias only)
#define NCHUNK (NCODES / 64)  // 64 column chunks

static __device__ inline unsigned short f2bf(float v) {
    __hip_bfloat16 h = __float2bfloat16(v);
    return __builtin_bit_cast(unsigned short, h);
}

// ---- kernel 1: student (B, D, T) fp32 -> Z (M=B*T, K=D) bf16, tiled transpose ----
__global__ void transpose_convert(const float* __restrict__ sf, unsigned short* __restrict__ Z) {
    __shared__ float tile[32][33];
    int b = blockIdx.z;
    int t0 = blockIdx.x * 32;
    int d0 = blockIdx.y * 32;
    int tx = threadIdx.x, ty = threadIdx.y;  // 32 x 8
    const float* src = sf + (size_t)b * ND * NT;
#pragma unroll
    for (int i = 0; i < 4; i++) {
        int d = d0 + ty + i * 8;
        tile[tx][ty + i * 8] = src[(size_t)d * NT + t0 + tx];
    }
    __syncthreads();
    unsigned short* dst = Z + (size_t)b * NT * ND;
#pragma unroll
    for (int i = 0; i < 4; i++) {
        int t = t0 + ty + i * 8;
        // wait: we need tile[d_local][t_local] with d_local = tx here
        dst[(size_t)t * ND + d0 + tx] = f2bf(tile[tx][ty + i * 8]);
    }
}
// NOTE on the above: read phase stores tile[tx][ty+i*8] = src[d=(d0+ty+i*8)][t=t0+tx],
// i.e. tile[t_local][d_local]. Write phase reads tile[tx][ty+i*8] = value at
// t_local=tx?? -- that would be wrong. Corrected below by swapping indices in read phase.

// Correct transpose (used instead of the above):
__global__ void transpose_convert2(const float* __restrict__ sf, unsigned short* __restrict__ Z) {
    __shared__ float tile[32][33];  // tile[d_local][t_local]
    int b = blockIdx.z;
    int t0 = blockIdx.x * 32;
    int d0 = blockIdx.y * 32;
    int tx = threadIdx.x, ty = threadIdx.y;  // 32 x 8
    const float* src = sf + (size_t)b * ND * NT;
#pragma unroll
    for (int i = 0; i < 4; i++) {
        int dl = ty + i * 8;
        tile[dl][tx] = src[(size_t)(d0 + dl) * NT + t0 + tx];  // coalesced along t (tx)
    }
    __syncthreads();
    unsigned short* dst = Z + (size_t)b * NT * ND;
#pragma unroll
    for (int i = 0; i < 4; i++) {
        int tl = ty + i * 8;
        dst[(size_t)(t0 + tl) * ND + d0 + tx] = f2bf(tile[tx][tl]);  // coalesced along d (tx)
    }
}

// ---- kernel 2: student row norms ||z_m||^2 in fp32 ----
__global__ void student_norms(const float* __restrict__ sf, float* __restrict__ znorm) {
    int idx = blockIdx.x * blockDim.x + threadIdx.x;  // m in [0, NM)
    int b = idx >> 11;       // / NT
    int t = idx & (NT - 1);  // % NT
    const float* src = sf + (size_t)b * ND * NT + t;
    float s = 0.0f;
#pragma unroll 8
    for (int d = 0; d < ND; d++) {
        float v = src[(size_t)d * NT];
        s += v * v;
    }
    znorm[idx] = s;
}

// ---- kernel 3: codebook -> bf16 + code norms ----
__global__ void codebook_prep(const float* __restrict__ cb, unsigned short* __restrict__ Cb,
                              float* __restrict__ cnorm) {
    int w = threadIdx.x >> 6;
    int lane = threadIdx.x & 63;
    int row = blockIdx.x * 4 + w;
    const float* src = cb + (size_t)row * ND;
    unsigned short* dst = Cb + (size_t)row * ND;
    float s = 0.0f;
#pragma unroll
    for (int i = 0; i < 8; i++) {
        float v = src[lane + i * 64];
        dst[lane + i * 64] = f2bf(v);
        s += v * v;
    }
#pragma unroll
    for (int off = 1; off < 64; off <<= 1) s += __shfl_xor(s, off);
    if (lane == 0) cnorm[row] = s;
}

// ---- kernel 4: main MFMA GEMM + fused min-epilogue ----
__global__ __launch_bounds__(256, 2) void triplet_main(
    const unsigned short* __restrict__ Z, const unsigned short* __restrict__ Cb,
    const float* __restrict__ cnorm, const int* __restrict__ teacher,
    float* __restrict__ negpart, float* __restrict__ pospart) {
    __shared__ unsigned short As[BM * LDT];
    __shared__ unsigned short Bs[BN * LDT];

    const int m0 = blockIdx.y * BM;
    const int n0 = blockIdx.x * BN;
    const int tid = threadIdx.x;
    const int wave = tid >> 6, lane = tid & 63;
    const int wr = wave >> 1, wc = wave & 1;
    const int l15 = lane & 15, quad = lane >> 4;

    f32x4 acc[4][4] = {};

    const int s0 = tid * 2;  // each thread stages 2 x 8-bf16 segments per tile

    for (int kt = 0; kt < ND / BK; kt++) {
        int k0 = kt * BK;
#pragma unroll
        for (int i = 0; i < 2; i++) {
            int s = s0 + i;
            int row = s >> 2, cg = (s & 3) * 8;
            uint4 va = *(const uint4*)(Z + (size_t)(m0 + row) * ND + k0 + cg);
            *(uint4*)&As[row * LDT + cg] = va;
            uint4 vb = *(const uint4*)(Cb + (size_t)(n0 + row) * ND + k0 + cg);
            *(uint4*)&Bs[row * LDT + cg] = vb;
        }
        __syncthreads();

        bf16x8 afr[4], bfr[4];
#pragma unroll
        for (int mi = 0; mi < 4; mi++) {
            int mrow = wr * 64 + mi * 16 + l15;
            afr[mi] = *(const bf16x8*)&As[mrow * LDT + quad * 8];
        }
#pragma unroll
        for (int ni = 0; ni < 4; ni++) {
            int nrow = wc * 64 + ni * 16 + l15;
            bfr[ni] = *(const bf16x8*)&Bs[nrow * LDT + quad * 8];
        }
#pragma unroll
        for (int mi = 0; mi < 4; mi++)
#pragma unroll
            for (int ni = 0; ni < 4; ni++)
                acc[mi][ni] = __builtin_amdgcn_mfma_f32_16x16x32_bf16(afr[mi], bfr[ni], acc[mi][ni], 0, 0, 0);
        __syncthreads();
    }

    // epilogue: per row min over this block's 64-col chunk of (cnorm - 2*dot),
    // with the teacher code excluded (captured separately as pos).
    const float INF = __builtin_inff();
    float cn[4];
    int ncol[4];
#pragma unroll
    for (int ni = 0; ni < 4; ni++) {
        ncol[ni] = n0 + wc * 64 + ni * 16 + l15;
        cn[ni] = cnorm[ncol[ni]];
    }
    const int chunk = (n0 >> 6) + wc;  // global 64-col chunk id in [0, 64)

#pragma unroll
    for (int mi = 0; mi < 4; mi++) {
#pragma unroll
        for (int r = 0; r < 4; r++) {
            int m = m0 + wr * 64 + mi * 16 + quad * 4 + r;  // C/D layout: row = quad*4 + reg
            int tch = teacher[m];
            float minv = INF, posv = INF;
#pragma unroll
            for (int ni = 0; ni < 4; ni++) {
                float val = cn[ni] - 2.0f * acc[mi][ni][r];
                bool ist = (ncol[ni] == tch);
                minv = fminf(minv, ist ? INF : val);
                posv = fminf(posv, ist ? val : INF);
            }
            // min across the 16 columns (lanes differing in bits 0..3 share a row)
#pragma unroll
            for (int off = 1; off < 16; off <<= 1) {
                minv = fminf(minv, __shfl_xor(minv, off));
                posv = fminf(posv, __shfl_xor(posv, off));
            }
            if (l15 == 0) {
                negpart[(size_t)chunk * NM + m] = minv;
                pospart[(size_t)chunk * NM + m] = posv;
            }
        }
    }
}

// ---- kernel 5: per-row reduce over chunks -> masked triplet block sums ----
__global__ void reduce_rows(const float* __restrict__ negpart, const float* __restrict__ pospart,
                            const float* __restrict__ znorm, const int* __restrict__ lengths,
                            float* __restrict__ blocksums) {
    int m = blockIdx.x * 256 + threadIdx.x;
    const float INF = __builtin_inff();
    float minv = INF, posv = INF;
#pragma unroll 8
    for (int c = 0; c < NCHUNK; c++) {
        minv = fminf(minv, negpart[(size_t)c * NM + m]);  // coalesced across m
        posv = fminf(posv, pospart[(size_t)c * NM + m]);
    }
    float rz = znorm[m];
    float negd = sqrtf(fmaxf(rz + minv, 1e-12f));
    float posd = sqrtf(fmaxf(rz + posv, 1e-12f));
    float tri = fmaxf(posd - negd + MARGIN_F, 0.0f);
    int b = m >> 11;
    int t = m & (NT - 1);
    int flen = lengths[b] / ENC_STRIDE;
    float val = (t < flen) ? tri : 0.0f;

    __shared__ float red[4];
#pragma unroll
    for (int off = 1; off < 64; off <<= 1) val += __shfl_xor(val, off);
    int lane = threadIdx.x & 63, w = threadIdx.x >> 6;
    if (lane == 0) red[w] = val;
    __syncthreads();
    if (threadIdx.x == 0) blocksums[blockIdx.x] = red[0] + red[1] + red[2] + red[3];
}

// ---- kernel 6: finalize ----
__global__ void finalize(const float* __restrict__ blocksums, const int* __restrict__ lengths,
                         float* __restrict__ out) {
    float s = (threadIdx.x < NM / 256) ? blocksums[threadIdx.x] : 0.0f;
#pragma unroll
    for (int off = 1; off < 64; off <<= 1) s += __shfl_xor(s, off);
    if (threadIdx.x == 0) {
        float cnt = 0.0f;
        for (int b = 0; b < NB; b++) cnt += (float)(lengths[b] / ENC_STRIDE);
        out[0] = s / (cnt + 1e-8f);
    }
}

extern "C" void kernel_launch(void* const* d_in, const int* in_sizes, int n_in,
                              void* d_out, int out_size, void* d_ws, size_t ws_size,
                              hipStream_t stream) {
    const float* sf = (const float*)d_in[0];
    const int* teacher = (const int*)d_in[1];
    const float* cb = (const float*)d_in[2];
    const int* lengths = (const int*)d_in[3];

    char* ws = (char*)d_ws;
    // layout (bytes)
    unsigned short* Z = (unsigned short*)(ws);                 // 16,777,216
    unsigned short* Cb = (unsigned short*)(ws + 16777216);     //  4,194,304
    float* znorm = (float*)(ws + 20971520);                    //     65,536
    float* cnorm = (float*)(ws + 21037056);                    //     16,384
    float* negpart = (float*)(ws + 21053440);                  //  4,194,304
    float* pospart = (float*)(ws + 25247744);                  //  4,194,304
    float* blocksums = (float*)(ws + 29442048);                //        256

    transpose_convert2<<<dim3(NT / 32, ND / 32, NB), dim3(32, 8), 0, stream>>>(sf, Z);
    student_norms<<<NM / 256, 256, 0, stream>>>(sf, znorm);
    codebook_prep<<<NCODES / 4, 256, 0, stream>>>(cb, Cb, cnorm);
    triplet_main<<<dim3(NCODES / BN, NM / BM), 256, 0, stream>>>(Z, Cb, cnorm, teacher, negpart, pospart);
    reduce_rows<<<NM / 256, 256, 0, stream>>>(negpart, pospart, znorm, lengths, blocksums);
    finalize<<<1, 64, 0, stream>>>(blocksums, lengths, (float*)d_out);
}

// Round 2
// 187.253 us; speedup vs baseline: 1.2208x; 1.2208x over previous
//
#include <hip/hip_runtime.h>
#include <hip/hip_bf16.h>

typedef __bf16 bf16x8 __attribute__((ext_vector_type(8)));
typedef float f32x4 __attribute__((ext_vector_type(4)));

#define NB 8
#define ND 512
#define NT 2048
#define NCODES 4096
#define NM (NB * NT)          // 16384 rows
#define MARGIN_F 0.2f
#define ENC_STRIDE 320

#define BM 128
#define BN 128
#define BK 32
#define LDT 32                // PACKED LDS row stride (required by global_load_lds lane mapping)
#define NCHUNK (NCODES / 64)  // 64 column chunks

static __device__ inline unsigned short f2bf(float v) {
    __hip_bfloat16 h = __float2bfloat16(v);
    return __builtin_bit_cast(unsigned short, h);
}

// async 16B global -> LDS (HW: lds dest = wave-uniform base + lane*16)
static __device__ inline void async_copy16(const void* g, void* l) {
    __builtin_amdgcn_global_load_lds(
        (const __attribute__((address_space(1))) unsigned int*)g,
        (__attribute__((address_space(3))) unsigned int*)l, 16, 0, 0);
}

// ---- kernel 1: transpose (B,D,T) fp32 -> Z (M,K) bf16, fused partial row-norms ----
// npart[d_group][m] = sum over 32 d's of z^2  (16 groups, deterministic — no atomics)
__global__ void transpose_norm(const float* __restrict__ sf, unsigned short* __restrict__ Z,
                               float* __restrict__ npart) {
    __shared__ float tile[32][33];  // tile[d_local][t_local]
    __shared__ float red[8][32];
    int b = blockIdx.z;
    int t0 = blockIdx.x * 32;
    int d0 = blockIdx.y * 32;
    int tx = threadIdx.x, ty = threadIdx.y;  // 32 x 8
    const float* src = sf + (size_t)b * ND * NT;
    float s = 0.0f;
#pragma unroll
    for (int i = 0; i < 4; i++) {
        int dl = ty + i * 8;
        float v = src[(size_t)(d0 + dl) * NT + t0 + tx];  // coalesced along t (tx)
        tile[dl][tx] = v;
        s += v * v;
    }
    red[ty][tx] = s;
    __syncthreads();
    unsigned short* dst = Z + (size_t)b * NT * ND;
#pragma unroll
    for (int i = 0; i < 4; i++) {
        int tl = ty + i * 8;
        dst[(size_t)(t0 + tl) * ND + d0 + tx] = f2bf(tile[tx][tl]);  // coalesced along d (tx)
    }
    if (ty == 0) {
        float zn = 0.0f;
#pragma unroll
        for (int j = 0; j < 8; j++) zn += red[j][tx];
        npart[(size_t)(d0 >> 5) * NM + (size_t)b * NT + t0 + tx] = zn;  // coalesced
    }
}

// ---- kernel 2: codebook -> bf16 + code norms ----
__global__ void codebook_prep(const float* __restrict__ cb, unsigned short* __restrict__ Cb,
                              float* __restrict__ cnorm) {
    int w = threadIdx.x >> 6;
    int lane = threadIdx.x & 63;
    int row = blockIdx.x * 4 + w;
    const float* src = cb + (size_t)row * ND;
    unsigned short* dst = Cb + (size_t)row * ND;
    float s = 0.0f;
#pragma unroll
    for (int i = 0; i < 8; i++) {
        float v = src[lane + i * 64];
        dst[lane + i * 64] = f2bf(v);
        s += v * v;
    }
#pragma unroll
    for (int off = 1; off < 64; off <<= 1) s += __shfl_xor(s, off);
    if (lane == 0) cnorm[row] = s;
}

// ---- kernel 3: main MFMA GEMM (global_load_lds staging) + fused min-epilogue ----
__global__ __launch_bounds__(256, 2) void triplet_main(
    const unsigned short* __restrict__ Z, const unsigned short* __restrict__ Cb,
    const float* __restrict__ cnorm, const int* __restrict__ teacher,
    float* __restrict__ negpart, float* __restrict__ pospart) {
    __shared__ unsigned short As[BM * LDT];  // 8 KB, packed
    __shared__ unsigned short Bs[BN * LDT];  // 8 KB, packed

    const int m0 = blockIdx.y * BM;
    const int n0 = blockIdx.x * BN;
    const int tid = threadIdx.x;
    const int wave = tid >> 6, lane = tid & 63;
    const int wr = wave >> 1, wc = wave & 1;
    const int l15 = lane & 15, quad = lane >> 4;

    f32x4 acc[4][4] = {};

    // staging map: tile is 128 rows x 64 B. Each thread DMAs 2 x 16B segments
    // per tile. Segment o (bytes): o1 = wave*2048 + lane*16, o2 = o1 + 1024.
    // LDS base passed per-call is wave-uniform; HW adds lane*16.
    const int o1 = wave * 2048 + lane * 16;
    const int o2 = o1 + 1024;
    const int rowA1 = o1 >> 6, colE1 = (o1 & 63) >> 1;
    const int rowA2 = o2 >> 6, colE2 = (o2 & 63) >> 1;
    const unsigned short* gA1 = Z + (size_t)(m0 + rowA1) * ND + colE1;
    const unsigned short* gA2 = Z + (size_t)(m0 + rowA2) * ND + colE2;
    const unsigned short* gB1 = Cb + (size_t)(n0 + rowA1) * ND + colE1;
    const unsigned short* gB2 = Cb + (size_t)(n0 + rowA2) * ND + colE2;
    char* lA1 = (char*)As + wave * 2048;
    char* lA2 = lA1 + 1024;
    char* lB1 = (char*)Bs + wave * 2048;
    char* lB2 = lB1 + 1024;

    for (int kt = 0; kt < ND / BK; kt++) {
        async_copy16(gA1, lA1);
        async_copy16(gA2, lA2);
        async_copy16(gB1, lB1);
        async_copy16(gB2, lB2);
        gA1 += BK; gA2 += BK; gB1 += BK; gB2 += BK;
        __syncthreads();  // compiler emits vmcnt(0) drain before barrier

        bf16x8 afr[4], bfr[4];
#pragma unroll
        for (int mi = 0; mi < 4; mi++) {
            int mrow = wr * 64 + mi * 16 + l15;
            afr[mi] = *(const bf16x8*)&As[mrow * LDT + quad * 8];
        }
#pragma unroll
        for (int ni = 0; ni < 4; ni++) {
            int nrow = wc * 64 + ni * 16 + l15;
            bfr[ni] = *(const bf16x8*)&Bs[nrow * LDT + quad * 8];
        }
#pragma unroll
        for (int mi = 0; mi < 4; mi++)
#pragma unroll
            for (int ni = 0; ni < 4; ni++)
                acc[mi][ni] = __builtin_amdgcn_mfma_f32_16x16x32_bf16(afr[mi], bfr[ni], acc[mi][ni], 0, 0, 0);
        __syncthreads();
    }

    // epilogue: per row, min over this wave's 64-col chunk of (cnorm - 2*dot),
    // teacher code excluded (captured separately as pos).
    const float INF = __builtin_inff();
    float cn[4];
    int ncol[4];
#pragma unroll
    for (int ni = 0; ni < 4; ni++) {
        ncol[ni] = n0 + wc * 64 + ni * 16 + l15;
        cn[ni] = cnorm[ncol[ni]];
    }
    const int chunk = (n0 >> 6) + wc;  // global 64-col chunk id in [0, 64)

#pragma unroll
    for (int mi = 0; mi < 4; mi++) {
#pragma unroll
        for (int r = 0; r < 4; r++) {
            int m = m0 + wr * 64 + mi * 16 + quad * 4 + r;  // C/D layout: row = quad*4 + reg
            int tch = teacher[m];
            float minv = INF, posv = INF;
#pragma unroll
            for (int ni = 0; ni < 4; ni++) {
                float val = cn[ni] - 2.0f * acc[mi][ni][r];
                bool ist = (ncol[ni] == tch);
                minv = fminf(minv, ist ? INF : val);
                posv = fminf(posv, ist ? val : INF);
            }
#pragma unroll
            for (int off = 1; off < 16; off <<= 1) {
                minv = fminf(minv, __shfl_xor(minv, off));
                posv = fminf(posv, __shfl_xor(posv, off));
            }
            if (l15 == 0) {
                negpart[(size_t)chunk * NM + m] = minv;
                pospart[(size_t)chunk * NM + m] = posv;
            }
        }
    }
}

// ---- kernel 4: per-row reduce (256 blocks x 256 thr; 4 chunk-groups/block) ----
__global__ void reduce_rows2(const float* __restrict__ negpart, const float* __restrict__ pospart,
                             const float* __restrict__ npart, const int* __restrict__ lengths,
                             float* __restrict__ blocksums) {
    const float INF = __builtin_inff();
    int t = threadIdx.x;
    int r = t & 63, g = t >> 6;
    int m = blockIdx.x * 64 + r;
    float minv = INF, posv = INF;
#pragma unroll 4
    for (int c = g * 16; c < g * 16 + 16; c++) {
        minv = fminf(minv, negpart[(size_t)c * NM + m]);  // coalesced across r
        posv = fminf(posv, pospart[(size_t)c * NM + m]);
    }
    float zn = 0.0f;
#pragma unroll
    for (int j = g * 4; j < g * 4 + 4; j++) zn += npart[(size_t)j * NM + m];

    __shared__ float sneg[4][64], spos[4][64], szn[4][64];
    sneg[g][r] = minv; spos[g][r] = posv; szn[g][r] = zn;
    __syncthreads();
    if (g == 0) {
        minv = fminf(fminf(sneg[0][r], sneg[1][r]), fminf(sneg[2][r], sneg[3][r]));
        posv = fminf(fminf(spos[0][r], spos[1][r]), fminf(spos[2][r], spos[3][r]));
        zn = szn[0][r] + szn[1][r] + szn[2][r] + szn[3][r];
        float negd = sqrtf(fmaxf(zn + minv, 1e-12f));
        float posd = sqrtf(fmaxf(zn + posv, 1e-12f));
        float tri = fmaxf(posd - negd + MARGIN_F, 0.0f);
        int b = m >> 11;
        int tt = m & (NT - 1);
        int flen = lengths[b] / ENC_STRIDE;
        float val = (tt < flen) ? tri : 0.0f;
#pragma unroll
        for (int off = 1; off < 64; off <<= 1) val += __shfl_xor(val, off);
        if (r == 0) blocksums[blockIdx.x] = val;
    }
}

// ---- kernel 5: finalize over 256 block sums ----
__global__ void finalize(const float* __restrict__ blocksums, const int* __restrict__ lengths,
                         float* __restrict__ out) {
    int t = threadIdx.x;  // 256
    float s = blocksums[t];
#pragma unroll
    for (int off = 1; off < 64; off <<= 1) s += __shfl_xor(s, off);
    __shared__ float red[4];
    int lane = t & 63, w = t >> 6;
    if (lane == 0) red[w] = s;
    __syncthreads();
    if (t == 0) {
        float cnt = 0.0f;
        for (int b = 0; b < NB; b++) cnt += (float)(lengths[b] / ENC_STRIDE);
        out[0] = (red[0] + red[1] + red[2] + red[3]) / (cnt + 1e-8f);
    }
}

extern "C" void kernel_launch(void* const* d_in, const int* in_sizes, int n_in,
                              void* d_out, int out_size, void* d_ws, size_t ws_size,
                              hipStream_t stream) {
    const float* sf = (const float*)d_in[0];
    const int* teacher = (const int*)d_in[1];
    const float* cb = (const float*)d_in[2];
    const int* lengths = (const int*)d_in[3];

    char* ws = (char*)d_ws;
    unsigned short* Z = (unsigned short*)(ws);                 // 16,777,216 B
    unsigned short* Cb = (unsigned short*)(ws + 16777216);     //  4,194,304 B
    float* cnorm = (float*)(ws + 20971520);                    //     16,384 B
    float* npart = (float*)(ws + 20987904);                    //  1,048,576 B (16 x NM)
    float* negpart = (float*)(ws + 22036480);                  //  4,194,304 B
    float* pospart = (float*)(ws + 26230784);                  //  4,194,304 B
    float* blocksums = (float*)(ws + 30425088);                //      1,024 B

    transpose_norm<<<dim3(NT / 32, ND / 32, NB), dim3(32, 8), 0, stream>>>(sf, Z, npart);
    codebook_prep<<<NCODES / 4, 256, 0, stream>>>(cb, Cb, cnorm);
    triplet_main<<<dim3(NCODES / BN, NM / BM), 256, 0, stream>>>(Z, Cb, cnorm, teacher, negpart, pospart);
    reduce_rows2<<<NM / 64, 256, 0, stream>>>(negpart, pospart, npart, lengths, blocksums);
    finalize<<<1, 256, 0, stream>>>(blocksums, lengths, (float*)d_out);
}